// Round 3
// baseline (37.399 us; speedup 1.0000x reference)
//
#include <hip/hip_runtime.h>

// PureAddShiftMP: 3x one-hot 3x3 convs + crop == shifted channel-gather adds.
// offsets (dy,dx): p0=(-1,-1), p1=(-1,0), p2=(0,-1)
// out_g[n,o,y,x] = sum_k x[n,3o+k, y+dy_{(k+g)%3}, x+dx_{(k+g)%3}]
// Thread coarsening: each thread emits a 4-row x 4-col strip; rows pipeline
// through registers so each input row is loaded once per thread (5 loads-rows
// for 4 output rows instead of 8).

#define PER_GROUP 8388608L    // 8*256*64*64

typedef float f4 __attribute__((ext_vector_type(4)));

__global__ __launch_bounds__(256) void shift3_kernel(
    const float* __restrict__ xin, float* __restrict__ out)
{
    unsigned t = blockIdx.x * 256u + threadIdx.x;  // 0..524287
    int xq = (int)(t & 15);          // x0/4
    int s  = (int)((t >> 4) & 15);   // y-strip (4 rows each)
    int o  = (int)((t >> 8) & 255);
    int n  = (int)(t >> 16);
    int x0 = xq << 2;
    int y0 = s << 2;

    const float* base = xin + (((size_t)n * 768 + 3 * (size_t)o) << 12);
    const float ymask = (s == 0) ? 0.0f : 1.0f;
    const float xmask = (xq == 0) ? 0.0f : 1.0f;
    const int rowm = ((s == 0) ? 0 : (y0 - 1)) << 6;

    // A* = row y-1 context (aligned vec + shifted-in scalar from lane-1)
    f4 A0, A1, A2; float a0s, a1s, a2s;
    {
        const float* r = base + rowm + x0;
        A0 = *reinterpret_cast<const f4*>(r);
        A1 = *reinterpret_cast<const f4*>(r + 4096);
        A2 = *reinterpret_cast<const f4*>(r + 8192);
        A0 *= ymask; A1 *= ymask; A2 *= ymask;
        a0s = __shfl_up(A0.w, 1, 64) * xmask;
        a1s = __shfl_up(A1.w, 1, 64) * xmask;
        a2s = __shfl_up(A2.w, 1, 64) * xmask;
    }

    size_t obase = (((size_t)n * 256 + (size_t)o) << 12) + ((size_t)y0 << 6) + (size_t)x0;

    #pragma unroll
    for (int j = 0; j < 4; ++j) {
        const float* r = base + ((y0 + j) << 6) + x0;
        f4 B0 = *reinterpret_cast<const f4*>(r);
        f4 B1 = *reinterpret_cast<const f4*>(r + 4096);
        f4 B2 = *reinterpret_cast<const f4*>(r + 8192);
        float b0s = __shfl_up(B0.w, 1, 64) * xmask;
        float b1s = __shfl_up(B1.w, 1, 64) * xmask;
        float b2s = __shfl_up(B2.w, 1, 64) * xmask;

        // p0[k] = {aks, Ak.xyz}; p1[k] = Ak; p2[k] = {bks, Bk.xyz}
        f4 o0 = (f4){a0s, A0.x, A0.y, A0.z} + A1 + (f4){b2s, B2.x, B2.y, B2.z};
        f4 o1 = A0 + (f4){b1s, B1.x, B1.y, B1.z} + (f4){a2s, A2.x, A2.y, A2.z};
        f4 o2 = (f4){b0s, B0.x, B0.y, B0.z} + (f4){a1s, A1.x, A1.y, A1.z} + A2;

        float* op = out + obase + ((size_t)j << 6);
        __builtin_nontemporal_store(o0, reinterpret_cast<f4*>(op));
        __builtin_nontemporal_store(o1, reinterpret_cast<f4*>(op + PER_GROUP));
        __builtin_nontemporal_store(o2, reinterpret_cast<f4*>(op + 2 * PER_GROUP));

        A0 = B0; A1 = B1; A2 = B2;
        a0s = b0s; a1s = b1s; a2s = b2s;
    }
}

extern "C" void kernel_launch(void* const* d_in, const int* in_sizes, int n_in,
                              void* d_out, int out_size, void* d_ws, size_t ws_size,
                              hipStream_t stream) {
    const float* x = (const float*)d_in[0];
    float* out = (float*)d_out;
    // 8*256*16*16 = 524288 threads -> 2048 blocks of 256
    shift3_kernel<<<2048, 256, 0, stream>>>(x, out);
}

// Round 4
// 34.824 us; speedup vs baseline: 1.0739x; 1.0739x over previous
//
#include <hip/hip_runtime.h>

// PureAddShiftMP: NK=3 one-hot 3x3 convs + center-crop == shifted channel-gather adds.
// offsets (dy,dx): p0=(-1,-1), p1=(-1,0), p2=(0,-1)
// out_g[n,o,y,x] = sum_k x[n,3o+k, y+dy_{(k+g)%3}, x+dx_{(k+g)%3}]
//
// R4 = R2 structure (wave-contiguous 1KB loads/stores, shfl for x-1 shift)
// WITHOUT non-temporal stores: out (100.7MB) + x (100.7MB) fit in 256MB L3,
// so letting stores write-allocate should keep steady-state HBM traffic ~0
// across graph replays.

#define CIN 768
#define COUT 256
#define PER_GROUP 8388608L    // 8*256*64*64

typedef float f4 __attribute__((ext_vector_type(4)));

__global__ __launch_bounds__(256) void shift3_kernel(
    const float* __restrict__ xin, float* __restrict__ out)
{
    // thread t handles 4 consecutive x pixels of one (n, o, y)
    unsigned t = blockIdx.x * 256u + threadIdx.x;   // 0 .. 2097151
    int xq = (int)(t & 15);          // x / 4
    int yy = (int)((t >> 4) & 63);
    int o  = (int)((t >> 10) & 255);
    int n  = (int)(t >> 18);
    int x0 = xq << 2;

    const float* base = xin + (((size_t)n * CIN + 3 * (size_t)o) << 12);
    const float ymask = (yy == 0) ? 0.0f : 1.0f;   // row y-1 exists?
    const float xmask = (xq == 0) ? 0.0f : 1.0f;   // col x-1 exists?
    const int rm = ((yy == 0) ? 0 : (yy - 1)) << 6; // clamped row y-1 (masked)
    const int r  = yy << 6;                          // row y

    f4 p0[3], p1[3], p2[3];
    #pragma unroll
    for (int k = 0; k < 3; ++k) {
        const float* c = base + (k << 12);
        f4 M = *reinterpret_cast<const f4*>(c + rm + x0);
        f4 R = *reinterpret_cast<const f4*>(c + r + x0);
        M.x *= ymask; M.y *= ymask; M.z *= ymask; M.w *= ymask;
        // neighbor-lane shift: previous lane (same row) holds x0-1 in its .w
        float m0 = __shfl_up(M.w, 1, 64) * xmask;
        float r0 = __shfl_up(R.w, 1, 64) * xmask;
        p1[k] = M;                       // (-1, 0)
        p0[k] = (f4){m0, M.x, M.y, M.z}; // (-1,-1)
        p2[k] = (f4){r0, R.x, R.y, R.z}; // ( 0,-1)
    }

    f4 o0 = p0[0] + p1[1] + p2[2];
    f4 o1 = p1[0] + p2[1] + p0[2];
    f4 o2 = p2[0] + p0[1] + p1[2];

    size_t oidx = (((size_t)n * COUT + (size_t)o) << 12) + ((size_t)yy << 6) + (size_t)x0;
    // normal (cached) stores: let out dwell in L3 across replays
    *reinterpret_cast<f4*>(out + oidx)                 = o0;
    *reinterpret_cast<f4*>(out + oidx + PER_GROUP)     = o1;
    *reinterpret_cast<f4*>(out + oidx + 2 * PER_GROUP) = o2;
}

extern "C" void kernel_launch(void* const* d_in, const int* in_sizes, int n_in,
                              void* d_out, int out_size, void* d_ws, size_t ws_size,
                              hipStream_t stream) {
    const float* x = (const float*)d_in[0];
    float* out = (float*)d_out;
    // total threads = 8*256*64*16 = 2,097,152 -> 8192 blocks of 256
    shift3_kernel<<<8192, 256, 0, stream>>>(x, out);
}

// Round 5
// 33.159 us; speedup vs baseline: 1.1278x; 1.0502x over previous
//
#include <hip/hip_runtime.h>

// PureAddShiftMP: NK=3 one-hot 3x3 convs + center-crop == shifted channel-gather adds.
// offsets (dy,dx): p0=(-1,-1), p1=(-1,0), p2=(0,-1)
// out_g[n,o,y,x] = sum_k x[n,3o+k, y+dy_{(k+g)%3}, x+dx_{(k+g)%3}]
//
// R5: shfl-free (clamped unaligned loads + cndmask edge fixup) + XCD-aware
// block swizzle so each XCD owns 256 contiguous (n,o) planes.

#define CIN 768
#define COUT 256
#define PER_GROUP 8388608L    // 8*256*64*64

typedef float f4 __attribute__((ext_vector_type(4)));

__global__ __launch_bounds__(256) void shift3_kernel(
    const float* __restrict__ xin, float* __restrict__ out)
{
    // XCD swizzle: 8192 blocks, 8 XCDs, 1024 consecutive work-blocks per XCD
    unsigned bid = blockIdx.x;
    unsigned wb  = (bid & 7u) * 1024u + (bid >> 3);

    unsigned t = wb * 256u + threadIdx.x;   // 0 .. 2097151
    int xq = (int)(t & 15);          // x / 4
    int yy = (int)((t >> 4) & 63);
    int o  = (int)((t >> 10) & 255);
    int n  = (int)(t >> 18);
    int x0 = xq << 2;

    const float* base = xin + (((size_t)n * CIN + 3 * (size_t)o) << 12);
    const float ymask = (yy == 0) ? 0.0f : 1.0f;     // row y-1 exists?
    const bool  xsel  = (xq != 0);                   // col x-1 exists?
    const int rm = ((yy == 0) ? 0 : (yy - 1)) << 6;  // clamped row y-1
    const int r  = yy << 6;                          // row y
    const int xu = x0 - (xsel ? 1 : 0);              // clamped unaligned col

    f4 p0[3], p1[3], p2[3];
    #pragma unroll
    for (int k = 0; k < 3; ++k) {
        const float* c = base + (k << 12);
        f4 Ma = *reinterpret_cast<const f4*>(c + rm + x0);  // aligned row y-1
        f4 Mu = *reinterpret_cast<const f4*>(c + rm + xu);  // row y-1, x-1
        f4 Ru = *reinterpret_cast<const f4*>(c + r  + xu);  // row y,   x-1
        Ma *= ymask;
        Mu *= ymask;
        p1[k] = Ma;                                   // (-1, 0)
        f4 q0, q2;                                    // edge fixup for xq==0:
        q0.x = xsel ? Mu.x : 0.0f;                    //   Mu/Ru were loaded
        q0.y = xsel ? Mu.y : Mu.x;                    //   aligned (xu==x0),
        q0.z = xsel ? Mu.z : Mu.y;                    //   so shift elems right
        q0.w = xsel ? Mu.w : Mu.z;                    //   and zero the first
        q2.x = xsel ? Ru.x : 0.0f;
        q2.y = xsel ? Ru.y : Ru.x;
        q2.z = xsel ? Ru.z : Ru.y;
        q2.w = xsel ? Ru.w : Ru.z;
        p0[k] = q0;                                   // (-1,-1)
        p2[k] = q2;                                   // ( 0,-1)
    }

    f4 o0 = p0[0] + p1[1] + p2[2];
    f4 o1 = p1[0] + p2[1] + p0[2];
    f4 o2 = p2[0] + p0[1] + p1[2];

    size_t oidx = (((size_t)n * COUT + (size_t)o) << 12) + ((size_t)yy << 6) + (size_t)x0;
    *reinterpret_cast<f4*>(out + oidx)                 = o0;
    *reinterpret_cast<f4*>(out + oidx + PER_GROUP)     = o1;
    *reinterpret_cast<f4*>(out + oidx + 2 * PER_GROUP) = o2;
}

extern "C" void kernel_launch(void* const* d_in, const int* in_sizes, int n_in,
                              void* d_out, int out_size, void* d_ws, size_t ws_size,
                              hipStream_t stream) {
    const float* x = (const float*)d_in[0];
    float* out = (float*)d_out;
    // total threads = 8*256*64*16 = 2,097,152 -> 8192 blocks of 256
    shift3_kernel<<<8192, 256, 0, stream>>>(x, out);
}